// Round 14
// baseline (263.768 us; speedup 1.0000x reference)
//
#include <hip/hip_runtime.h>
#include <hip/hip_bf16.h>
#include <hip/hip_fp16.h>

constexpr int NR = 12288;   // nodes
constexpr int KF = 256;     // in features
constexpr int DF = 128;     // out features
constexpr int CH = 32;      // column chunks (48x32 = 1536 blocks = 3 exact rounds)
constexpr int CW = NR / CH; // 384 cols per chunk
constexpr int NSTEP = CW / 32;      // 12
constexpr int ROWS = 256;   // Q-rows per flash block (8 waves x 2 subtiles x 16 rows)
constexpr int BMW = NR / 32;        // bitmask words per row (384)
#define NEGBIG (-1e30f)
#define LOG2E 1.44269504088896340736f

typedef __attribute__((ext_vector_type(8))) __bf16 bf16x8;
typedef __attribute__((ext_vector_type(4))) float  f32x4;

__device__ __forceinline__ unsigned short f2bf(float f) {
    union { float f; unsigned u; } v; v.f = f;
    unsigned r = v.u + 0x7FFFu + ((v.u >> 16) & 1u);
    return (unsigned short)(r >> 16);
}

__device__ __forceinline__ void gload16(const void* g, void* l) {
    __builtin_amdgcn_global_load_lds(
        (const __attribute__((address_space(1))) void*)g,
        (__attribute__((address_space(3))) void*)l, 16, 0, 0);
}

// monotone float<->uint map for atomicMax-based global max
__device__ __forceinline__ unsigned fmap(float f) {
    unsigned b = __float_as_uint(f);
    return (b & 0x80000000u) ? ~b : (b | 0x80000000u);
}
__device__ __forceinline__ float funmap(unsigned m) {
    unsigned b = (m & 0x80000000u) ? (m ^ 0x80000000u) : ~m;
    return __uint_as_float(b);
}

// ---------- Kernel 0: adj (int32 0/1) -> bitmask. Pure stream, ~604 MB read.
__global__ __launch_bounds__(256) void k_compress(
    const int* __restrict__ adj, unsigned* __restrict__ bm, unsigned* __restrict__ gmxu)
{
    if (blockIdx.x == 0 && threadIdx.x == 0) gmxu[0] = 0u;  // < fmap(any finite)
    const int lane = threadIdx.x & 63;
    const unsigned sh = (lane & 7) * 4;
    size_t i = (size_t)blockIdx.x * 256 + threadIdx.x;
    const size_t total4 = (size_t)NR * NR / 4;
    const size_t stride = (size_t)gridDim.x * 256;
    const int4* a4 = (const int4*)adj;
    for (; i < total4; i += stride) {
        int4 a = a4[i];
        unsigned nib = (unsigned)(a.x > 0) | ((unsigned)(a.y > 0) << 1)
                     | ((unsigned)(a.z > 0) << 2) | ((unsigned)(a.w > 0) << 3);
        unsigned v = nib << sh;
        v |= __shfl_xor(v, 1);
        v |= __shfl_xor(v, 2);
        v |= __shfl_xor(v, 4);
        if ((lane & 7) == 0) bm[i >> 3] = v;
    }
}

// ---------- Kernel A: h = x@W -> hbT(bf16,T), s1,s2 (PRE-SCALED by log2e),
// gmax via atomicMax -----------------------------------------------------------
__global__ __launch_bounds__(256) void k_gemm_h(
    const float* __restrict__ x, const float* __restrict__ W,
    const float* __restrict__ a1, const float* __restrict__ a2,
    unsigned short* __restrict__ hbT, float* __restrict__ s1, float* __restrict__ s2,
    unsigned* __restrict__ gmxu)
{
    __shared__ __align__(16) float xs[64][65];
    __shared__ __align__(16) float ws[64][132];
    const int t  = threadIdx.x;
    const int tx = t & 15, ty = t >> 4;
    const int lane = t & 63;
    const int rowbase = blockIdx.x * 64;

    float acc[4][8];
#pragma unroll
    for (int i = 0; i < 4; ++i)
#pragma unroll
        for (int j = 0; j < 8; ++j) acc[i][j] = 0.f;

    for (int kt = 0; kt < KF; kt += 64) {
        {   // stage x tile [64][64]
            int row = t >> 2, k0 = (t & 3) * 16;
            const float4* src = (const float4*)(x + (size_t)(rowbase + row) * KF + kt + k0);
            float4 v0 = src[0], v1 = src[1], v2 = src[2], v3 = src[3];
            xs[row][k0+ 0]=v0.x; xs[row][k0+ 1]=v0.y; xs[row][k0+ 2]=v0.z; xs[row][k0+ 3]=v0.w;
            xs[row][k0+ 4]=v1.x; xs[row][k0+ 5]=v1.y; xs[row][k0+ 6]=v1.z; xs[row][k0+ 7]=v1.w;
            xs[row][k0+ 8]=v2.x; xs[row][k0+ 9]=v2.y; xs[row][k0+10]=v2.z; xs[row][k0+11]=v2.w;
            xs[row][k0+12]=v3.x; xs[row][k0+13]=v3.y; xs[row][k0+14]=v3.z; xs[row][k0+15]=v3.w;
        }
        {   // stage W tile [64][128]
            int k = t >> 2, c0 = (t & 3) * 32;
            const float4* src = (const float4*)(W + (size_t)(kt + k) * DF + c0);
#pragma unroll
            for (int j = 0; j < 8; ++j)
                *(float4*)&ws[k][c0 + j * 4] = src[j];
        }
        __syncthreads();
#pragma unroll 4
        for (int k = 0; k < 64; ++k) {
            float xv[4];
#pragma unroll
            for (int ri = 0; ri < 4; ++ri) xv[ri] = xs[ty * 4 + ri][k];
            float4 w0 = *(float4*)&ws[k][tx * 8];
            float4 w1 = *(float4*)&ws[k][tx * 8 + 4];
#pragma unroll
            for (int ri = 0; ri < 4; ++ri) {
                acc[ri][0] += xv[ri] * w0.x; acc[ri][1] += xv[ri] * w0.y;
                acc[ri][2] += xv[ri] * w0.z; acc[ri][3] += xv[ri] * w0.w;
                acc[ri][4] += xv[ri] * w1.x; acc[ri][5] += xv[ri] * w1.y;
                acc[ri][6] += xv[ri] * w1.z; acc[ri][7] += xv[ri] * w1.w;
            }
        }
        __syncthreads();
    }
#pragma unroll
    for (int ci = 0; ci < 8; ++ci) {
        int col = tx * 8 + ci;
        ushort4 u;
        u.x = f2bf(acc[0][ci]); u.y = f2bf(acc[1][ci]);
        u.z = f2bf(acc[2][ci]); u.w = f2bf(acc[3][ci]);
        *(ushort4*)(hbT + (size_t)col * NR + rowbase + ty * 4) = u;
    }
    float4 a1lo = *(const float4*)(a1 + tx * 8), a1hi = *(const float4*)(a1 + tx * 8 + 4);
    float4 a2lo = *(const float4*)(a2 + tx * 8), a2hi = *(const float4*)(a2 + tx * 8 + 4);
    float lmax = NEGBIG;
#pragma unroll
    for (int ri = 0; ri < 4; ++ri) {
        float p1 = acc[ri][0]*a1lo.x + acc[ri][1]*a1lo.y + acc[ri][2]*a1lo.z + acc[ri][3]*a1lo.w
                 + acc[ri][4]*a1hi.x + acc[ri][5]*a1hi.y + acc[ri][6]*a1hi.z + acc[ri][7]*a1hi.w;
        float p2 = acc[ri][0]*a2lo.x + acc[ri][1]*a2lo.y + acc[ri][2]*a2lo.z + acc[ri][3]*a2lo.w
                 + acc[ri][4]*a2hi.x + acc[ri][5]*a2hi.y + acc[ri][6]*a2hi.z + acc[ri][7]*a2hi.w;
#pragma unroll
        for (int off = 8; off > 0; off >>= 1) {
            p1 += __shfl_xor(p1, off);
            p2 += __shfl_xor(p2, off);
        }
        p1 *= LOG2E; p2 *= LOG2E;   // log2 domain: exp(x) == exp2(x*log2e)
        if (tx == 0) {
            s1[rowbase + ty * 4 + ri] = p1;
            s2[rowbase + ty * 4 + ri] = p2;
        }
        lmax = fmaxf(lmax, p1);
    }
    lmax = fmaxf(lmax, __shfl_xor(lmax, 16));
    lmax = fmaxf(lmax, __shfl_xor(lmax, 32));
    if (lane == 0) atomicMax(gmxu, fmap(lmax));
}

// ---------- Kernel B: flash from BITMASK, 2 row-subtiles/wave, log2 domain. --
// 256 rows/block (8 waves), 512 thr, 2 blk/CU; grid 48x32 = 3 exact rounds.
// One bfr load feeds TWO MFMAs. Ring-3, uniform vmcnt(1). fp16 numb out.
__global__ __launch_bounds__(512, 4) void k_flash(
    const unsigned* __restrict__ bm, const unsigned short* __restrict__ hbT,
    const float* __restrict__ s1, const float* __restrict__ s2,
    const unsigned* __restrict__ gmxu,
    __half* __restrict__ num, float* __restrict__ lC)
{
    __shared__ __align__(16) unsigned short hbtring[3][4096]; // 8KB/slot
    __shared__ __align__(16) unsigned       bmlds[ROWS][12];  // 12 KB (2-way max, free)
    __shared__ __align__(16) float          s1lds[CW];

    const int t    = threadIdx.x;
    const int wid  = t >> 6, lane = t & 63;
    const int r    = lane & 15, g = lane >> 4;
    const int rowb = blockIdx.x * ROWS;
    const int prowA = rowb + wid * 16 + r;
    const int prowB = prowA + 128;
    const int chunk = blockIdx.y;
    const int j0 = chunk * CW;

    // one-time: stage s1 chunk + bitmask tile [256 rows][12 words]
    if (t < CW / 4) *(float4*)&s1lds[t * 4] = *(const float4*)(s1 + j0 + t * 4);
#pragma unroll
    for (int i = 0; i < 2; ++i) {
        int idx = i * 512 + t;               // 768 uint4 = 256 rows x 3
        if (idx < 768) {
            int brow = idx / 3, bk = idx % 3;
            uint4 w = *(const uint4*)(bm + (size_t)(rowb + brow) * BMW + chunk * NSTEP + bk * 4);
            *(uint4*)&bmlds[brow][bk * 4] = w;   // row stride 48B -> 16B aligned
        }
    }

    const float gm   = funmap(gmxu[0]);
    const float s2rA = s2[prowA];
    const float s2rB = s2[prowB];
    const float zubA = s2rA + gm, zubB = s2rB + gm;
    const float MiA  = fmaxf(zubA, 0.2f * zubA);
    const float MiB  = fmaxf(zubB, 0.2f * zubB);
    // algebraic form: arg = max(s - C1, 0.2*s - C2)   (all log2-domain)
    const float nC1A = s2rA - MiA, nC2A = 0.2f * s2rA - MiA;
    const float nC1B = s2rB - MiB, nC2B = 0.2f * s2rB - MiB;

    // ---- hbT staging: wave wid stages feats wid*16..+16 via 1 gload16
    const int hrow  = wid * 16 + (lane >> 2);
    const int hcol8 = ((lane & 3) ^ ((lane >> 3) & 3)) * 8;
    const unsigned short* hgp0 = hbT + (size_t)hrow * NR + j0 + hcol8;
    const int hldso0 = wid * 16 * 64;
    const int h_base = r * 64 + ((g ^ ((r >> 1) & 3)) * 16);    // + f*1024

#define ISSUE(st) do { \
        const int sl_ = (st) % 3; \
        const size_t go_ = (size_t)(((st) % NSTEP) * 32); \
        gload16(hgp0 + go_, (char*)&hbtring[sl_][0] + hldso0); \
    } while (0)

    float lsumA = 0.f, lsumB = 0.f;
    f32x4 accA[8], accB[8];
#pragma unroll
    for (int f = 0; f < 8; ++f) {
        accA[f] = f32x4{0.f, 0.f, 0.f, 0.f};
        accB[f] = f32x4{0.f, 0.f, 0.f, 0.f};
    }

    ISSUE(0);
    ISSUE(1);

    const unsigned* bmrowA = &bmlds[wid * 16 + r][0];
    const unsigned* bmrowB = &bmlds[128 + wid * 16 + r][0];
    const unsigned gsh = g * 8;

    for (int j = 0; j < NSTEP; ++j) {
        asm volatile("s_waitcnt vmcnt(1) lgkmcnt(0)" ::: "memory");
        __builtin_amdgcn_s_barrier();
        __builtin_amdgcn_sched_barrier(0);
        ISSUE(j + 2);   // slot (j+2)%3 == (j-1)%3, consumed before the barrier

        const unsigned mwA = bmrowA[j] >> gsh;
        const unsigned mwB = bmrowB[j] >> gsh;
        const float4 Sa = *(const float4*)&s1lds[j * 32 + g * 8];
        const float4 Sb = *(const float4*)&s1lds[j * 32 + g * 8 + 4];

        bf16x8 pfA, pfB;
#define PROC(mw_, nC1_, nC2_, lsum_, pf_, bi, ss, idx) { \
            float a_  = (ss) + (nC1_); \
            float b_  = __builtin_fmaf(0.2f, (ss), (nC2_)); \
            float q   = exp2f(fmaxf(a_, b_)); \
            float p   = (((mw_) >> (bi)) & 1u) ? q : 0.f; \
            lsum_ += p; \
            pf_[idx] = (__bf16)p; }
        PROC(mwA, nC1A, nC2A, lsumA, pfA, 0, Sa.x, 0) PROC(mwA, nC1A, nC2A, lsumA, pfA, 1, Sa.y, 1)
        PROC(mwA, nC1A, nC2A, lsumA, pfA, 2, Sa.z, 2) PROC(mwA, nC1A, nC2A, lsumA, pfA, 3, Sa.w, 3)
        PROC(mwA, nC1A, nC2A, lsumA, pfA, 4, Sb.x, 4) PROC(mwA, nC1A, nC2A, lsumA, pfA, 5, Sb.y, 5)
        PROC(mwA, nC1A, nC2A, lsumA, pfA, 6, Sb.z, 6) PROC(mwA, nC1A, nC2A, lsumA, pfA, 7, Sb.w, 7)
        PROC(mwB, nC1B, nC2B, lsumB, pfB, 0, Sa.x, 0) PROC(mwB, nC1B, nC2B, lsumB, pfB, 1, Sa.y, 1)
        PROC(mwB, nC1B, nC2B, lsumB, pfB, 2, Sa.z, 2) PROC(mwB, nC1B, nC2B, lsumB, pfB, 3, Sa.w, 3)
        PROC(mwB, nC1B, nC2B, lsumB, pfB, 4, Sb.x, 4) PROC(mwB, nC1B, nC2B, lsumB, pfB, 5, Sb.y, 5)
        PROC(mwB, nC1B, nC2B, lsumB, pfB, 6, Sb.z, 6) PROC(mwB, nC1B, nC2B, lsumB, pfB, 7, Sb.w, 7)
#undef PROC

        const int sl = j % 3;
        const char* hb = (const char*)&hbtring[sl][0] + h_base;
#pragma unroll
        for (int f = 0; f < 8; ++f) {
            bf16x8 bfr = *(const bf16x8*)(hb + f * 1024);   // ONE load, TWO MFMAs
            accA[f] = __builtin_amdgcn_mfma_f32_16x16x32_bf16(pfA, bfr, accA[f], 0, 0, 0);
            accB[f] = __builtin_amdgcn_mfma_f32_16x16x32_bf16(pfB, bfr, accB[f], 0, 0, 0);
        }
    }
#undef ISSUE

    lsumA += __shfl_xor(lsumA, 16);
    lsumA += __shfl_xor(lsumA, 32);
    lsumB += __shfl_xor(lsumB, 16);
    lsumB += __shfl_xor(lsumB, 32);
    if (g == 0) {
        lC[(size_t)chunk * NR + prowA] = lsumA;
        lC[(size_t)chunk * NR + prowB] = lsumB;
    }

    __half* nb = num + (size_t)chunk * NR * DF;
#pragma unroll
    for (int f = 0; f < 8; ++f)
#pragma unroll
        for (int q = 0; q < 4; ++q) {
            int rowA = rowb + wid * 16 + g * 4 + q;   // C/D layout: row=(lane>>4)*4+reg
            nb[(size_t)rowA * DF + f * 16 + r]         = __float2half(accA[f][q]);
            nb[(size_t)(rowA + 128) * DF + f * 16 + r] = __float2half(accB[f][q]);
        }
}

// ---------- Kernel C: combine chunk partials (shared M_i -> plain sums) ------
__global__ __launch_bounds__(256) void k_comb(
    const __half* __restrict__ num, const float* __restrict__ lC,
    float* __restrict__ out)
{
    const int t   = threadIdx.x;
    const int row = blockIdx.x * 2 + (t >> 7);
    const int f   = t & 127;
    float L = 0.f, o = 0.f;
    for (int c = 0; c < CH; ++c) {
        L += lC[(size_t)c * NR + row];
        o += __half2float(num[(size_t)c * NR * DF + (size_t)row * DF + f]);
    }
    out[(size_t)row * DF + f] = o / L;
}

extern "C" void kernel_launch(void* const* d_in, const int* in_sizes, int n_in,
                              void* d_out, int out_size, void* d_ws, size_t ws_size,
                              hipStream_t stream)
{
    const float* x   = (const float*)d_in[0];
    const int*   adj = (const int*)d_in[1];
    const float* W   = (const float*)d_in[2];
    const float* a1  = (const float*)d_in[3];
    const float* a2  = (const float*)d_in[4];
    float* out = (float*)d_out;

    char* p = (char*)d_ws;
    unsigned short* hbT = (unsigned short*)p; p += (size_t)DF * NR * 2;
    unsigned*       bmw = (unsigned*)p;       p += (size_t)NR * BMW * 4;
    float*          s1  = (float*)p;          p += (size_t)NR * 4;
    float*          s2  = (float*)p;          p += (size_t)NR * 4;
    unsigned*       gmxu = (unsigned*)p;      p += 256;
    __half*         numb = (__half*)p;        p += (size_t)CH * NR * DF * 2;
    float*          lC   = (float*)p;

    k_compress<<<2048, 256, 0, stream>>>(adj, bmw, gmxu);
    k_gemm_h<<<NR / 64, 256, 0, stream>>>(x, W, a1, a2, hbT, s1, s2, gmxu);
    k_flash<<<dim3(NR / ROWS, CH), 512, 0, stream>>>(bmw, hbT, s1, s2, gmxu, numb, lC);
    k_comb<<<NR / 2, 256, 0, stream>>>(numb, lC, out);
}

// Round 15
// 238.907 us; speedup vs baseline: 1.1041x; 1.1041x over previous
//
#include <hip/hip_runtime.h>
#include <hip/hip_bf16.h>
#include <hip/hip_fp16.h>

constexpr int NR = 12288;   // nodes
constexpr int KF = 256;     // in features
constexpr int DF = 128;     // out features
constexpr int CH = 16;      // column chunks
constexpr int CW = NR / CH; // 768 cols per chunk
constexpr int NSTEP = CW / 32;      // 24
constexpr int ROWS = 128;   // Q-rows per flash block (8 waves x 16 rows)
constexpr int BMW = NR / 32;        // bitmask words per row (384)
#define NEGBIG (-1e30f)
#define LOG2E 1.44269504088896340736f

typedef __attribute__((ext_vector_type(8))) __bf16 bf16x8;
typedef __attribute__((ext_vector_type(4))) float  f32x4;

__device__ __forceinline__ unsigned short f2bf(float f) {
    union { float f; unsigned u; } v; v.f = f;
    unsigned r = v.u + 0x7FFFu + ((v.u >> 16) & 1u);
    return (unsigned short)(r >> 16);
}

__device__ __forceinline__ void gload16(const void* g, void* l) {
    __builtin_amdgcn_global_load_lds(
        (const __attribute__((address_space(1))) void*)g,
        (__attribute__((address_space(3))) void*)l, 16, 0, 0);
}

// monotone float<->uint map for atomicMax-based global max
__device__ __forceinline__ unsigned fmap(float f) {
    unsigned b = __float_as_uint(f);
    return (b & 0x80000000u) ? ~b : (b | 0x80000000u);
}
__device__ __forceinline__ float funmap(unsigned m) {
    unsigned b = (m & 0x80000000u) ? (m ^ 0x80000000u) : ~m;
    return __uint_as_float(b);
}

// ---------- Kernel 0: adj (int32 0/1) -> bitmask. Pure stream, ~604 MB read.
__global__ __launch_bounds__(256) void k_compress(
    const int* __restrict__ adj, unsigned* __restrict__ bm, unsigned* __restrict__ gmxu)
{
    if (blockIdx.x == 0 && threadIdx.x == 0) gmxu[0] = 0u;  // < fmap(any finite)
    const int lane = threadIdx.x & 63;
    const unsigned sh = (lane & 7) * 4;
    size_t i = (size_t)blockIdx.x * 256 + threadIdx.x;
    const size_t total4 = (size_t)NR * NR / 4;
    const size_t stride = (size_t)gridDim.x * 256;
    const int4* a4 = (const int4*)adj;
    for (; i < total4; i += stride) {
        int4 a = a4[i];
        unsigned nib = (unsigned)(a.x > 0) | ((unsigned)(a.y > 0) << 1)
                     | ((unsigned)(a.z > 0) << 2) | ((unsigned)(a.w > 0) << 3);
        unsigned v = nib << sh;
        v |= __shfl_xor(v, 1);
        v |= __shfl_xor(v, 2);
        v |= __shfl_xor(v, 4);
        if ((lane & 7) == 0) bm[i >> 3] = v;
    }
}

// ---------- Kernel A: h = x@W -> hbT(bf16,T), s1,s2 (log2e-scaled), gmax -----
__global__ __launch_bounds__(256) void k_gemm_h(
    const float* __restrict__ x, const float* __restrict__ W,
    const float* __restrict__ a1, const float* __restrict__ a2,
    unsigned short* __restrict__ hbT, float* __restrict__ s1, float* __restrict__ s2,
    unsigned* __restrict__ gmxu)
{
    __shared__ __align__(16) float xs[64][65];
    __shared__ __align__(16) float ws[64][132];
    const int t  = threadIdx.x;
    const int tx = t & 15, ty = t >> 4;
    const int lane = t & 63;
    const int rowbase = blockIdx.x * 64;

    float acc[4][8];
#pragma unroll
    for (int i = 0; i < 4; ++i)
#pragma unroll
        for (int j = 0; j < 8; ++j) acc[i][j] = 0.f;

    for (int kt = 0; kt < KF; kt += 64) {
        {   // stage x tile [64][64]
            int row = t >> 2, k0 = (t & 3) * 16;
            const float4* src = (const float4*)(x + (size_t)(rowbase + row) * KF + kt + k0);
            float4 v0 = src[0], v1 = src[1], v2 = src[2], v3 = src[3];
            xs[row][k0+ 0]=v0.x; xs[row][k0+ 1]=v0.y; xs[row][k0+ 2]=v0.z; xs[row][k0+ 3]=v0.w;
            xs[row][k0+ 4]=v1.x; xs[row][k0+ 5]=v1.y; xs[row][k0+ 6]=v1.z; xs[row][k0+ 7]=v1.w;
            xs[row][k0+ 8]=v2.x; xs[row][k0+ 9]=v2.y; xs[row][k0+10]=v2.z; xs[row][k0+11]=v2.w;
            xs[row][k0+12]=v3.x; xs[row][k0+13]=v3.y; xs[row][k0+14]=v3.z; xs[row][k0+15]=v3.w;
        }
        {   // stage W tile [64][128]
            int k = t >> 2, c0 = (t & 3) * 32;
            const float4* src = (const float4*)(W + (size_t)(kt + k) * DF + c0);
#pragma unroll
            for (int j = 0; j < 8; ++j)
                *(float4*)&ws[k][c0 + j * 4] = src[j];
        }
        __syncthreads();
#pragma unroll 4
        for (int k = 0; k < 64; ++k) {
            float xv[4];
#pragma unroll
            for (int ri = 0; ri < 4; ++ri) xv[ri] = xs[ty * 4 + ri][k];
            float4 w0 = *(float4*)&ws[k][tx * 8];
            float4 w1 = *(float4*)&ws[k][tx * 8 + 4];
#pragma unroll
            for (int ri = 0; ri < 4; ++ri) {
                acc[ri][0] += xv[ri] * w0.x; acc[ri][1] += xv[ri] * w0.y;
                acc[ri][2] += xv[ri] * w0.z; acc[ri][3] += xv[ri] * w0.w;
                acc[ri][4] += xv[ri] * w1.x; acc[ri][5] += xv[ri] * w1.y;
                acc[ri][6] += xv[ri] * w1.z; acc[ri][7] += xv[ri] * w1.w;
            }
        }
        __syncthreads();
    }
#pragma unroll
    for (int ci = 0; ci < 8; ++ci) {
        int col = tx * 8 + ci;
        ushort4 u;
        u.x = f2bf(acc[0][ci]); u.y = f2bf(acc[1][ci]);
        u.z = f2bf(acc[2][ci]); u.w = f2bf(acc[3][ci]);
        *(ushort4*)(hbT + (size_t)col * NR + rowbase + ty * 4) = u;
    }
    float4 a1lo = *(const float4*)(a1 + tx * 8), a1hi = *(const float4*)(a1 + tx * 8 + 4);
    float4 a2lo = *(const float4*)(a2 + tx * 8), a2hi = *(const float4*)(a2 + tx * 8 + 4);
    float lmax = NEGBIG;
#pragma unroll
    for (int ri = 0; ri < 4; ++ri) {
        float p1 = acc[ri][0]*a1lo.x + acc[ri][1]*a1lo.y + acc[ri][2]*a1lo.z + acc[ri][3]*a1lo.w
                 + acc[ri][4]*a1hi.x + acc[ri][5]*a1hi.y + acc[ri][6]*a1hi.z + acc[ri][7]*a1hi.w;
        float p2 = acc[ri][0]*a2lo.x + acc[ri][1]*a2lo.y + acc[ri][2]*a2lo.z + acc[ri][3]*a2lo.w
                 + acc[ri][4]*a2hi.x + acc[ri][5]*a2hi.y + acc[ri][6]*a2hi.z + acc[ri][7]*a2hi.w;
#pragma unroll
        for (int off = 8; off > 0; off >>= 1) {
            p1 += __shfl_xor(p1, off);
            p2 += __shfl_xor(p2, off);
        }
        p1 *= LOG2E; p2 *= LOG2E;   // log2 domain: exp(x) == exp2(x*log2e)
        if (tx == 0) {
            s1[rowbase + ty * 4 + ri] = p1;
            s2[rowbase + ty * 4 + ri] = p2;
        }
        lmax = fmaxf(lmax, p1);
    }
    lmax = fmaxf(lmax, __shfl_xor(lmax, 16));
    lmax = fmaxf(lmax, __shfl_xor(lmax, 32));
    if (lane == 0) atomicMax(gmxu, fmap(lmax));
}

// ---------- Kernel B: flash from BITMASK (R10 structure + XCD-chunk affinity).
// 128 rows/block (8 waves x 16 rows), 512 thr, 2 blk/CU, grid 1536 = 3 rounds.
// Work remap: flat%8 = XCD -> each XCD owns 2 chunks; hbT slice (0.4 MB) stays
// hot in that XCD's L2 (no adj flood in this kernel). Ring-3, vmcnt(1).
__global__ __launch_bounds__(512, 4) void k_flash(
    const unsigned* __restrict__ bm, const unsigned short* __restrict__ hbT,
    const float* __restrict__ s1, const float* __restrict__ s2,
    const unsigned* __restrict__ gmxu,
    __half* __restrict__ num, float* __restrict__ lC)
{
    __shared__ __align__(16) unsigned short hbtring[3][4096]; // 8KB/slot
    __shared__ __align__(16) unsigned       bmlds[ROWS][28];  // 24 + pad (2-way, free)
    __shared__ __align__(16) float          s1lds[CW];

    const int t    = threadIdx.x;
    const int wid  = t >> 6, lane = t & 63;
    const int r    = lane & 15, g = lane >> 4;
    // XCD-affinity remap: flat%8 = XCD (dispatch round-robin heuristic)
    const int flat  = blockIdx.x + blockIdx.y * gridDim.x;   // 0..1535
    const int xcd   = flat & 7;
    const int slot  = flat >> 3;                             // 0..191
    const int chunk = xcd * 2 + (slot >= 96 ? 1 : 0);
    const int rowblk = (slot >= 96) ? slot - 96 : slot;
    const int rowb  = rowblk * ROWS;
    const int prow  = rowb + wid * 16 + r;
    const int j0 = chunk * CW;

    // one-time: stage s1 chunk + bitmask tile [128 rows][24 words]
    if (t < CW / 4) *(float4*)&s1lds[t * 4] = *(const float4*)(s1 + j0 + t * 4);
#pragma unroll
    for (int i = 0; i < 2; ++i) {
        int idx = i * 512 + t;               // 768 uint4 = 128 rows x 6
        if (idx < 768) {
            int brow = idx / 6, bk = idx % 6;
            uint4 w = *(const uint4*)(bm + (size_t)(rowb + brow) * BMW + chunk * NSTEP + bk * 4);
            *(uint4*)&bmlds[brow][bk * 4] = w;   // 28%4==0 -> 16B aligned
        }
    }

    const float gm  = funmap(gmxu[0]);
    const float s2r = s2[prow];
    const float zub = s2r + gm;
    const float Mi  = fmaxf(zub, 0.2f * zub);   // lrelu(ub) >= every row logit (log2 dom)
    const float nC1 = s2r - Mi, nC2 = 0.2f * s2r - Mi;

    // ---- hbT staging: wave wid stages feats wid*16..+16 via 1 gload16
    const int hrow  = wid * 16 + (lane >> 2);
    const int hcol8 = ((lane & 3) ^ ((lane >> 3) & 3)) * 8;
    const unsigned short* hgp0 = hbT + (size_t)hrow * NR + j0 + hcol8;
    const int hldso0 = wid * 16 * 64;
    const int h_base = r * 64 + ((g ^ ((r >> 1) & 3)) * 16);    // + f*1024

#define ISSUE(st) do { \
        const int sl_ = (st) % 3; \
        const size_t go_ = (size_t)(((st) % NSTEP) * 32); \
        gload16(hgp0 + go_, (char*)&hbtring[sl_][0] + hldso0); \
    } while (0)

    float lsum = 0.f;
    f32x4 acc[8];
#pragma unroll
    for (int f = 0; f < 8; ++f) acc[f] = f32x4{0.f, 0.f, 0.f, 0.f};

    ISSUE(0);
    ISSUE(1);

    const unsigned* bmrow = &bmlds[wid * 16 + r][0];
    const unsigned gsh = g * 8;

    for (int j = 0; j < NSTEP; ++j) {
        // stage j landed when <=1 of this wave's vmem remain (stage j+1 only).
        asm volatile("s_waitcnt vmcnt(1) lgkmcnt(0)" ::: "memory");
        __builtin_amdgcn_s_barrier();
        __builtin_amdgcn_sched_barrier(0);
        ISSUE(j + 2);   // slot (j+2)%3 == (j-1)%3, consumed before the barrier

        const unsigned mw = bmrow[j] >> gsh;    // bits 0..7 = this lane's 8 cols
        const float4 Sa = *(const float4*)&s1lds[j * 32 + g * 8];
        const float4 Sb = *(const float4*)&s1lds[j * 32 + g * 8 + 4];

        bf16x8 pf;
#define PROC(bi, ss, idx) { \
            float a_ = (ss) + nC1; \
            float b_ = __builtin_fmaf(0.2f, (ss), nC2); \
            float q  = exp2f(fmaxf(a_, b_)); \
            float p  = ((mw >> (bi)) & 1u) ? q : 0.f; \
            lsum += p; \
            pf[idx] = (__bf16)p; }
        PROC(0, Sa.x, 0) PROC(1, Sa.y, 1)
        PROC(2, Sa.z, 2) PROC(3, Sa.w, 3)
        PROC(4, Sb.x, 4) PROC(5, Sb.y, 5)
        PROC(6, Sb.z, 6) PROC(7, Sb.w, 7)
#undef PROC

        const int sl = j % 3;
        const char* hb = (const char*)&hbtring[sl][0] + h_base;
#pragma unroll
        for (int f = 0; f < 8; ++f) {
            bf16x8 bfr = *(const bf16x8*)(hb + f * 1024);
            acc[f] = __builtin_amdgcn_mfma_f32_16x16x32_bf16(pf, bfr, acc[f], 0, 0, 0);
        }
    }
#undef ISSUE

    lsum += __shfl_xor(lsum, 16);
    lsum += __shfl_xor(lsum, 32);
    if (g == 0) lC[(size_t)chunk * NR + prow] = lsum;

    __half* nb = num + (size_t)chunk * NR * DF;
#pragma unroll
    for (int f = 0; f < 8; ++f)
#pragma unroll
        for (int q = 0; q < 4; ++q) {
            int row = rowb + wid * 16 + g * 4 + q;   // C/D layout: row=(lane>>4)*4+reg
            nb[(size_t)row * DF + f * 16 + r] = __float2half(acc[f][q]);
        }
}

// ---------- Kernel C: combine chunk partials (shared M_i -> plain sums) ------
__global__ __launch_bounds__(256) void k_comb(
    const __half* __restrict__ num, const float* __restrict__ lC,
    float* __restrict__ out)
{
    const int t   = threadIdx.x;
    const int row = blockIdx.x * 2 + (t >> 7);
    const int f   = t & 127;
    float L = 0.f, o = 0.f;
    for (int c = 0; c < CH; ++c) {
        L += lC[(size_t)c * NR + row];
        o += __half2float(num[(size_t)c * NR * DF + (size_t)row * DF + f]);
    }
    out[(size_t)row * DF + f] = o / L;
}

extern "C" void kernel_launch(void* const* d_in, const int* in_sizes, int n_in,
                              void* d_out, int out_size, void* d_ws, size_t ws_size,
                              hipStream_t stream)
{
    const float* x   = (const float*)d_in[0];
    const int*   adj = (const int*)d_in[1];
    const float* W   = (const float*)d_in[2];
    const float* a1  = (const float*)d_in[3];
    const float* a2  = (const float*)d_in[4];
    float* out = (float*)d_out;

    char* p = (char*)d_ws;
    unsigned short* hbT = (unsigned short*)p; p += (size_t)DF * NR * 2;
    unsigned*       bmw = (unsigned*)p;       p += (size_t)NR * BMW * 4;
    float*          s1  = (float*)p;          p += (size_t)NR * 4;
    float*          s2  = (float*)p;          p += (size_t)NR * 4;
    unsigned*       gmxu = (unsigned*)p;      p += 256;
    __half*         numb = (__half*)p;        p += (size_t)CH * NR * DF * 2;
    float*          lC   = (float*)p;

    k_compress<<<2048, 256, 0, stream>>>(adj, bmw, gmxu);
    k_gemm_h<<<NR / 64, 256, 0, stream>>>(x, W, a1, a2, hbT, s1, s2, gmxu);
    k_flash<<<dim3(96, CH), 512, 0, stream>>>(bmw, hbT, s1, s2, gmxu, numb, lC);
    k_comb<<<NR / 2, 256, 0, stream>>>(numb, lC, out);
}

// Round 16
// 237.702 us; speedup vs baseline: 1.1097x; 1.0051x over previous
//
#include <hip/hip_runtime.h>
#include <hip/hip_bf16.h>
#include <hip/hip_fp16.h>

constexpr int NR = 12288;   // nodes
constexpr int KF = 256;     // in features
constexpr int DF = 128;     // out features
constexpr int CH = 16;      // column chunks
constexpr int CW = NR / CH; // 768 cols per chunk
constexpr int NSTEP = CW / 32;      // 24
constexpr int ROWS = 128;   // Q-rows per flash block (8 waves x 16 rows)
constexpr int BMW = NR / 32;        // bitmask words per row (384)
#define NEGBIG (-1e30f)
#define LOG2E 1.44269504088896340736f

typedef __attribute__((ext_vector_type(8))) __bf16 bf16x8;
typedef __attribute__((ext_vector_type(4))) float  f32x4;

__device__ __forceinline__ unsigned short f2bf(float f) {
    union { float f; unsigned u; } v; v.f = f;
    unsigned r = v.u + 0x7FFFu + ((v.u >> 16) & 1u);
    return (unsigned short)(r >> 16);
}

__device__ __forceinline__ void gload16(const void* g, void* l) {
    __builtin_amdgcn_global_load_lds(
        (const __attribute__((address_space(1))) void*)g,
        (__attribute__((address_space(3))) void*)l, 16, 0, 0);
}

// monotone float<->uint map for atomicMax-based global max
__device__ __forceinline__ unsigned fmap(float f) {
    unsigned b = __float_as_uint(f);
    return (b & 0x80000000u) ? ~b : (b | 0x80000000u);
}
__device__ __forceinline__ float funmap(unsigned m) {
    unsigned b = (m & 0x80000000u) ? (m ^ 0x80000000u) : ~m;
    return __uint_as_float(b);
}

// ---------- Kernel 0: adj (int32 0/1) -> bitmask. Pure stream, ~604 MB read.
__global__ __launch_bounds__(256) void k_compress(
    const int* __restrict__ adj, unsigned* __restrict__ bm, unsigned* __restrict__ gmxu)
{
    if (blockIdx.x == 0 && threadIdx.x == 0) gmxu[0] = 0u;  // < fmap(any finite)
    const int lane = threadIdx.x & 63;
    const unsigned sh = (lane & 7) * 4;
    size_t i = (size_t)blockIdx.x * 256 + threadIdx.x;
    const size_t total4 = (size_t)NR * NR / 4;
    const size_t stride = (size_t)gridDim.x * 256;
    const int4* a4 = (const int4*)adj;
    for (; i < total4; i += stride) {
        int4 a = a4[i];
        unsigned nib = (unsigned)(a.x > 0) | ((unsigned)(a.y > 0) << 1)
                     | ((unsigned)(a.z > 0) << 2) | ((unsigned)(a.w > 0) << 3);
        unsigned v = nib << sh;
        v |= __shfl_xor(v, 1);
        v |= __shfl_xor(v, 2);
        v |= __shfl_xor(v, 4);
        if ((lane & 7) == 0) bm[i >> 3] = v;
    }
}

// ---------- Kernel A: h = x@W -> hbT(bf16,T), s1,s2 (log2e-scaled), gmax -----
__global__ __launch_bounds__(256) void k_gemm_h(
    const float* __restrict__ x, const float* __restrict__ W,
    const float* __restrict__ a1, const float* __restrict__ a2,
    unsigned short* __restrict__ hbT, float* __restrict__ s1, float* __restrict__ s2,
    unsigned* __restrict__ gmxu)
{
    __shared__ __align__(16) float xs[64][65];
    __shared__ __align__(16) float ws[64][132];
    const int t  = threadIdx.x;
    const int tx = t & 15, ty = t >> 4;
    const int lane = t & 63;
    const int rowbase = blockIdx.x * 64;

    float acc[4][8];
#pragma unroll
    for (int i = 0; i < 4; ++i)
#pragma unroll
        for (int j = 0; j < 8; ++j) acc[i][j] = 0.f;

    for (int kt = 0; kt < KF; kt += 64) {
        {   // stage x tile [64][64]
            int row = t >> 2, k0 = (t & 3) * 16;
            const float4* src = (const float4*)(x + (size_t)(rowbase + row) * KF + kt + k0);
            float4 v0 = src[0], v1 = src[1], v2 = src[2], v3 = src[3];
            xs[row][k0+ 0]=v0.x; xs[row][k0+ 1]=v0.y; xs[row][k0+ 2]=v0.z; xs[row][k0+ 3]=v0.w;
            xs[row][k0+ 4]=v1.x; xs[row][k0+ 5]=v1.y; xs[row][k0+ 6]=v1.z; xs[row][k0+ 7]=v1.w;
            xs[row][k0+ 8]=v2.x; xs[row][k0+ 9]=v2.y; xs[row][k0+10]=v2.z; xs[row][k0+11]=v2.w;
            xs[row][k0+12]=v3.x; xs[row][k0+13]=v3.y; xs[row][k0+14]=v3.z; xs[row][k0+15]=v3.w;
        }
        {   // stage W tile [64][128]
            int k = t >> 2, c0 = (t & 3) * 32;
            const float4* src = (const float4*)(W + (size_t)(kt + k) * DF + c0);
#pragma unroll
            for (int j = 0; j < 8; ++j)
                *(float4*)&ws[k][c0 + j * 4] = src[j];
        }
        __syncthreads();
#pragma unroll 4
        for (int k = 0; k < 64; ++k) {
            float xv[4];
#pragma unroll
            for (int ri = 0; ri < 4; ++ri) xv[ri] = xs[ty * 4 + ri][k];
            float4 w0 = *(float4*)&ws[k][tx * 8];
            float4 w1 = *(float4*)&ws[k][tx * 8 + 4];
#pragma unroll
            for (int ri = 0; ri < 4; ++ri) {
                acc[ri][0] += xv[ri] * w0.x; acc[ri][1] += xv[ri] * w0.y;
                acc[ri][2] += xv[ri] * w0.z; acc[ri][3] += xv[ri] * w0.w;
                acc[ri][4] += xv[ri] * w1.x; acc[ri][5] += xv[ri] * w1.y;
                acc[ri][6] += xv[ri] * w1.z; acc[ri][7] += xv[ri] * w1.w;
            }
        }
        __syncthreads();
    }
#pragma unroll
    for (int ci = 0; ci < 8; ++ci) {
        int col = tx * 8 + ci;
        ushort4 u;
        u.x = f2bf(acc[0][ci]); u.y = f2bf(acc[1][ci]);
        u.z = f2bf(acc[2][ci]); u.w = f2bf(acc[3][ci]);
        *(ushort4*)(hbT + (size_t)col * NR + rowbase + ty * 4) = u;
    }
    float4 a1lo = *(const float4*)(a1 + tx * 8), a1hi = *(const float4*)(a1 + tx * 8 + 4);
    float4 a2lo = *(const float4*)(a2 + tx * 8), a2hi = *(const float4*)(a2 + tx * 8 + 4);
    float lmax = NEGBIG;
#pragma unroll
    for (int ri = 0; ri < 4; ++ri) {
        float p1 = acc[ri][0]*a1lo.x + acc[ri][1]*a1lo.y + acc[ri][2]*a1lo.z + acc[ri][3]*a1lo.w
                 + acc[ri][4]*a1hi.x + acc[ri][5]*a1hi.y + acc[ri][6]*a1hi.z + acc[ri][7]*a1hi.w;
        float p2 = acc[ri][0]*a2lo.x + acc[ri][1]*a2lo.y + acc[ri][2]*a2lo.z + acc[ri][3]*a2lo.w
                 + acc[ri][4]*a2hi.x + acc[ri][5]*a2hi.y + acc[ri][6]*a2hi.z + acc[ri][7]*a2hi.w;
#pragma unroll
        for (int off = 8; off > 0; off >>= 1) {
            p1 += __shfl_xor(p1, off);
            p2 += __shfl_xor(p2, off);
        }
        p1 *= LOG2E; p2 *= LOG2E;   // log2 domain: exp(x) == exp2(x*log2e)
        if (tx == 0) {
            s1[rowbase + ty * 4 + ri] = p1;
            s2[rowbase + ty * 4 + ri] = p2;
        }
        lmax = fmaxf(lmax, p1);
    }
    lmax = fmaxf(lmax, __shfl_xor(lmax, 16));
    lmax = fmaxf(lmax, __shfl_xor(lmax, 32));
    if (lane == 0) atomicMax(gmxu, fmap(lmax));
}

// ---------- Kernel B: flash from BITMASK — exact R10 structure. --------------
// 128 rows/block (8 waves x 16 rows), 512 thr, 2 blk/CU, grid 96x16 = 1536
// blocks = exactly 3 rounds. Natural block mapping (dispatcher locality).
// Per-iter VMEM = 1 gload16/wave (hbT, L2-hot). Ring-3, counted vmcnt(1).
__global__ __launch_bounds__(512, 4) void k_flash(
    const unsigned* __restrict__ bm, const unsigned short* __restrict__ hbT,
    const float* __restrict__ s1, const float* __restrict__ s2,
    const unsigned* __restrict__ gmxu,
    __half* __restrict__ num, float* __restrict__ lC)
{
    __shared__ __align__(16) unsigned short hbtring[3][4096]; // 8KB/slot
    __shared__ __align__(16) unsigned       bmlds[ROWS][28];  // 24 + pad (2-way, free)
    __shared__ __align__(16) float          s1lds[CW];

    const int t    = threadIdx.x;
    const int wid  = t >> 6, lane = t & 63;
    const int r    = lane & 15, g = lane >> 4;
    const int rowb = blockIdx.x * ROWS;
    const int prow = rowb + wid * 16 + r;
    const int chunk = blockIdx.y;
    const int j0 = chunk * CW;

    // one-time: stage s1 chunk + bitmask tile [128 rows][24 words]
    if (t < CW / 4) *(float4*)&s1lds[t * 4] = *(const float4*)(s1 + j0 + t * 4);
#pragma unroll
    for (int i = 0; i < 2; ++i) {
        int idx = i * 512 + t;               // 768 uint4 = 128 rows x 6
        if (idx < 768) {
            int brow = idx / 6, bk = idx % 6;
            uint4 w = *(const uint4*)(bm + (size_t)(rowb + brow) * BMW + chunk * NSTEP + bk * 4);
            *(uint4*)&bmlds[brow][bk * 4] = w;   // 28%4==0 -> 16B aligned
        }
    }

    const float gm  = funmap(gmxu[0]);
    const float s2r = s2[prow];
    const float zub = s2r + gm;
    const float Mi  = fmaxf(zub, 0.2f * zub);   // lrelu(ub) >= every row logit (log2 dom)
    const float nC1 = s2r - Mi, nC2 = 0.2f * s2r - Mi;

    // ---- hbT staging: wave wid stages feats wid*16..+16 via 1 gload16
    const int hrow  = wid * 16 + (lane >> 2);
    const int hcol8 = ((lane & 3) ^ ((lane >> 3) & 3)) * 8;
    const unsigned short* hgp0 = hbT + (size_t)hrow * NR + j0 + hcol8;
    const int hldso0 = wid * 16 * 64;
    const int h_base = r * 64 + ((g ^ ((r >> 1) & 3)) * 16);    // + f*1024

#define ISSUE(st) do { \
        const int sl_ = (st) % 3; \
        const size_t go_ = (size_t)(((st) % NSTEP) * 32); \
        gload16(hgp0 + go_, (char*)&hbtring[sl_][0] + hldso0); \
    } while (0)

    float lsum = 0.f;
    f32x4 acc[8];
#pragma unroll
    for (int f = 0; f < 8; ++f) acc[f] = f32x4{0.f, 0.f, 0.f, 0.f};

    ISSUE(0);
    ISSUE(1);

    const unsigned* bmrow = &bmlds[wid * 16 + r][0];
    const unsigned gsh = g * 8;

    for (int j = 0; j < NSTEP; ++j) {
        // stage j landed when <=1 of this wave's vmem remain (stage j+1 only).
        asm volatile("s_waitcnt vmcnt(1) lgkmcnt(0)" ::: "memory");
        __builtin_amdgcn_s_barrier();
        __builtin_amdgcn_sched_barrier(0);
        ISSUE(j + 2);   // slot (j+2)%3 == (j-1)%3, consumed before the barrier

        const unsigned mw = bmrow[j] >> gsh;    // bits 0..7 = this lane's 8 cols
        const float4 Sa = *(const float4*)&s1lds[j * 32 + g * 8];
        const float4 Sb = *(const float4*)&s1lds[j * 32 + g * 8 + 4];

        bf16x8 pf;
#define PROC(bi, ss, idx) { \
            float a_ = (ss) + nC1; \
            float b_ = __builtin_fmaf(0.2f, (ss), nC2); \
            float q  = exp2f(fmaxf(a_, b_)); \
            float p  = ((mw >> (bi)) & 1u) ? q : 0.f; \
            lsum += p; \
            pf[idx] = (__bf16)p; }
        PROC(0, Sa.x, 0) PROC(1, Sa.y, 1)
        PROC(2, Sa.z, 2) PROC(3, Sa.w, 3)
        PROC(4, Sb.x, 4) PROC(5, Sb.y, 5)
        PROC(6, Sb.z, 6) PROC(7, Sb.w, 7)
#undef PROC

        const int sl = j % 3;
        const char* hb = (const char*)&hbtring[sl][0] + h_base;
#pragma unroll
        for (int f = 0; f < 8; ++f) {
            bf16x8 bfr = *(const bf16x8*)(hb + f * 1024);
            acc[f] = __builtin_amdgcn_mfma_f32_16x16x32_bf16(pf, bfr, acc[f], 0, 0, 0);
        }
    }
#undef ISSUE

    lsum += __shfl_xor(lsum, 16);
    lsum += __shfl_xor(lsum, 32);
    if (g == 0) lC[(size_t)chunk * NR + prow] = lsum;

    __half* nb = num + (size_t)chunk * NR * DF;
#pragma unroll
    for (int f = 0; f < 8; ++f)
#pragma unroll
        for (int q = 0; q < 4; ++q) {
            int row = rowb + wid * 16 + g * 4 + q;   // C/D layout: row=(lane>>4)*4+reg
            nb[(size_t)row * DF + f * 16 + r] = __float2half(acc[f][q]);
        }
}

// ---------- Kernel C: combine chunk partials (shared M_i -> plain sums) ------
__global__ __launch_bounds__(256) void k_comb(
    const __half* __restrict__ num, const float* __restrict__ lC,
    float* __restrict__ out)
{
    const int t   = threadIdx.x;
    const int row = blockIdx.x * 2 + (t >> 7);
    const int f   = t & 127;
    float L = 0.f, o = 0.f;
    for (int c = 0; c < CH; ++c) {
        L += lC[(size_t)c * NR + row];
        o += __half2float(num[(size_t)c * NR * DF + (size_t)row * DF + f]);
    }
    out[(size_t)row * DF + f] = o / L;
}

extern "C" void kernel_launch(void* const* d_in, const int* in_sizes, int n_in,
                              void* d_out, int out_size, void* d_ws, size_t ws_size,
                              hipStream_t stream)
{
    const float* x   = (const float*)d_in[0];
    const int*   adj = (const int*)d_in[1];
    const float* W   = (const float*)d_in[2];
    const float* a1  = (const float*)d_in[3];
    const float* a2  = (const float*)d_in[4];
    float* out = (float*)d_out;

    char* p = (char*)d_ws;
    unsigned short* hbT = (unsigned short*)p; p += (size_t)DF * NR * 2;
    unsigned*       bmw = (unsigned*)p;       p += (size_t)NR * BMW * 4;
    float*          s1  = (float*)p;          p += (size_t)NR * 4;
    float*          s2  = (float*)p;          p += (size_t)NR * 4;
    unsigned*       gmxu = (unsigned*)p;      p += 256;
    __half*         numb = (__half*)p;        p += (size_t)CH * NR * DF * 2;
    float*          lC   = (float*)p;

    k_compress<<<2048, 256, 0, stream>>>(adj, bmw, gmxu);
    k_gemm_h<<<NR / 64, 256, 0, stream>>>(x, W, a1, a2, hbT, s1, s2, gmxu);
    k_flash<<<dim3(NR / ROWS, CH), 512, 0, stream>>>(bmw, hbT, s1, s2, gmxu, numb, lC);
    k_comb<<<NR / 2, 256, 0, stream>>>(numb, lC, out);
}

// Round 17
// 227.380 us; speedup vs baseline: 1.1600x; 1.0454x over previous
//
#include <hip/hip_runtime.h>
#include <hip/hip_bf16.h>
#include <hip/hip_fp16.h>

constexpr int NR = 12288;   // nodes
constexpr int KF = 256;     // in features
constexpr int DF = 128;     // out features
constexpr int CH = 16;      // column chunks
constexpr int CW = NR / CH; // 768 cols per chunk
constexpr int NSTEP = CW / 32;      // 24
constexpr int ROWS = 128;   // Q-rows per flash block (8 waves x 16 rows)
constexpr int BMW = NR / 32;        // bitmask words per row (384)
#define NEGBIG (-1e30f)
#define LOG2E 1.44269504088896340736f

typedef __attribute__((ext_vector_type(8))) __bf16 bf16x8;
typedef __attribute__((ext_vector_type(4))) float  f32x4;

// fast exp2: single v_exp_f32 (libm exp2f drags in denormal fixup code --
// measured +15us over 151M calls in R16)
__device__ __forceinline__ float fexp2(float x) {
#if __has_builtin(__builtin_amdgcn_exp2f)
    return __builtin_amdgcn_exp2f(x);
#else
    return __expf(x * 0.69314718055994530942f);
#endif
}

__device__ __forceinline__ unsigned short f2bf(float f) {
    union { float f; unsigned u; } v; v.f = f;
    unsigned r = v.u + 0x7FFFu + ((v.u >> 16) & 1u);
    return (unsigned short)(r >> 16);
}

__device__ __forceinline__ void gload16(const void* g, void* l) {
    __builtin_amdgcn_global_load_lds(
        (const __attribute__((address_space(1))) void*)g,
        (__attribute__((address_space(3))) void*)l, 16, 0, 0);
}

// monotone float<->uint map for atomicMax-based global max
__device__ __forceinline__ unsigned fmap(float f) {
    unsigned b = __float_as_uint(f);
    return (b & 0x80000000u) ? ~b : (b | 0x80000000u);
}
__device__ __forceinline__ float funmap(unsigned m) {
    unsigned b = (m & 0x80000000u) ? (m ^ 0x80000000u) : ~m;
    return __uint_as_float(b);
}

// ---------- Kernel 0: adj (int32 0/1) -> bitmask. Pure stream, ~604 MB read.
__global__ __launch_bounds__(256) void k_compress(
    const int* __restrict__ adj, unsigned* __restrict__ bm, unsigned* __restrict__ gmxu)
{
    if (blockIdx.x == 0 && threadIdx.x == 0) gmxu[0] = 0u;  // < fmap(any finite)
    const int lane = threadIdx.x & 63;
    const unsigned sh = (lane & 7) * 4;
    size_t i = (size_t)blockIdx.x * 256 + threadIdx.x;
    const size_t total4 = (size_t)NR * NR / 4;
    const size_t stride = (size_t)gridDim.x * 256;
    const int4* a4 = (const int4*)adj;
    for (; i < total4; i += stride) {
        int4 a = a4[i];
        unsigned nib = (unsigned)(a.x > 0) | ((unsigned)(a.y > 0) << 1)
                     | ((unsigned)(a.z > 0) << 2) | ((unsigned)(a.w > 0) << 3);
        unsigned v = nib << sh;
        v |= __shfl_xor(v, 1);
        v |= __shfl_xor(v, 2);
        v |= __shfl_xor(v, 4);
        if ((lane & 7) == 0) bm[i >> 3] = v;
    }
}

// ---------- Kernel A: h = x@W -> hbT(bf16,T), s1,s2 (log2e-scaled), gmax -----
__global__ __launch_bounds__(256) void k_gemm_h(
    const float* __restrict__ x, const float* __restrict__ W,
    const float* __restrict__ a1, const float* __restrict__ a2,
    unsigned short* __restrict__ hbT, float* __restrict__ s1, float* __restrict__ s2,
    unsigned* __restrict__ gmxu)
{
    __shared__ __align__(16) float xs[64][65];
    __shared__ __align__(16) float ws[64][132];
    const int t  = threadIdx.x;
    const int tx = t & 15, ty = t >> 4;
    const int lane = t & 63;
    const int rowbase = blockIdx.x * 64;

    float acc[4][8];
#pragma unroll
    for (int i = 0; i < 4; ++i)
#pragma unroll
        for (int j = 0; j < 8; ++j) acc[i][j] = 0.f;

    for (int kt = 0; kt < KF; kt += 64) {
        {   // stage x tile [64][64]
            int row = t >> 2, k0 = (t & 3) * 16;
            const float4* src = (const float4*)(x + (size_t)(rowbase + row) * KF + kt + k0);
            float4 v0 = src[0], v1 = src[1], v2 = src[2], v3 = src[3];
            xs[row][k0+ 0]=v0.x; xs[row][k0+ 1]=v0.y; xs[row][k0+ 2]=v0.z; xs[row][k0+ 3]=v0.w;
            xs[row][k0+ 4]=v1.x; xs[row][k0+ 5]=v1.y; xs[row][k0+ 6]=v1.z; xs[row][k0+ 7]=v1.w;
            xs[row][k0+ 8]=v2.x; xs[row][k0+ 9]=v2.y; xs[row][k0+10]=v2.z; xs[row][k0+11]=v2.w;
            xs[row][k0+12]=v3.x; xs[row][k0+13]=v3.y; xs[row][k0+14]=v3.z; xs[row][k0+15]=v3.w;
        }
        {   // stage W tile [64][128]
            int k = t >> 2, c0 = (t & 3) * 32;
            const float4* src = (const float4*)(W + (size_t)(kt + k) * DF + c0);
#pragma unroll
            for (int j = 0; j < 8; ++j)
                *(float4*)&ws[k][c0 + j * 4] = src[j];
        }
        __syncthreads();
#pragma unroll 4
        for (int k = 0; k < 64; ++k) {
            float xv[4];
#pragma unroll
            for (int ri = 0; ri < 4; ++ri) xv[ri] = xs[ty * 4 + ri][k];
            float4 w0 = *(float4*)&ws[k][tx * 8];
            float4 w1 = *(float4*)&ws[k][tx * 8 + 4];
#pragma unroll
            for (int ri = 0; ri < 4; ++ri) {
                acc[ri][0] += xv[ri] * w0.x; acc[ri][1] += xv[ri] * w0.y;
                acc[ri][2] += xv[ri] * w0.z; acc[ri][3] += xv[ri] * w0.w;
                acc[ri][4] += xv[ri] * w1.x; acc[ri][5] += xv[ri] * w1.y;
                acc[ri][6] += xv[ri] * w1.z; acc[ri][7] += xv[ri] * w1.w;
            }
        }
        __syncthreads();
    }
#pragma unroll
    for (int ci = 0; ci < 8; ++ci) {
        int col = tx * 8 + ci;
        ushort4 u;
        u.x = f2bf(acc[0][ci]); u.y = f2bf(acc[1][ci]);
        u.z = f2bf(acc[2][ci]); u.w = f2bf(acc[3][ci]);
        *(ushort4*)(hbT + (size_t)col * NR + rowbase + ty * 4) = u;
    }
    float4 a1lo = *(const float4*)(a1 + tx * 8), a1hi = *(const float4*)(a1 + tx * 8 + 4);
    float4 a2lo = *(const float4*)(a2 + tx * 8), a2hi = *(const float4*)(a2 + tx * 8 + 4);
    float lmax = NEGBIG;
#pragma unroll
    for (int ri = 0; ri < 4; ++ri) {
        float p1 = acc[ri][0]*a1lo.x + acc[ri][1]*a1lo.y + acc[ri][2]*a1lo.z + acc[ri][3]*a1lo.w
                 + acc[ri][4]*a1hi.x + acc[ri][5]*a1hi.y + acc[ri][6]*a1hi.z + acc[ri][7]*a1hi.w;
        float p2 = acc[ri][0]*a2lo.x + acc[ri][1]*a2lo.y + acc[ri][2]*a2lo.z + acc[ri][3]*a2lo.w
                 + acc[ri][4]*a2hi.x + acc[ri][5]*a2hi.y + acc[ri][6]*a2hi.z + acc[ri][7]*a2hi.w;
#pragma unroll
        for (int off = 8; off > 0; off >>= 1) {
            p1 += __shfl_xor(p1, off);
            p2 += __shfl_xor(p2, off);
        }
        p1 *= LOG2E; p2 *= LOG2E;   // log2 domain: exp(x) == exp2(x*log2e)
        if (tx == 0) {
            s1[rowbase + ty * 4 + ri] = p1;
            s2[rowbase + ty * 4 + ri] = p2;
        }
        lmax = fmaxf(lmax, p1);
    }
    lmax = fmaxf(lmax, __shfl_xor(lmax, 16));
    lmax = fmaxf(lmax, __shfl_xor(lmax, 32));
    if (lane == 0) atomicMax(gmxu, fmap(lmax));
}

// ---------- Kernel B: flash from BITMASK — R10 structure. --------------------
// 128 rows/block (8 waves x 16 rows), 512 thr, 2 blk/CU, grid 96x16 = 1536
// blocks = exactly 3 rounds. Natural block mapping (dispatcher locality —
// R15/R16 A/B showed remapping is neutral-to-harmful).
// Per-iter VMEM = 1 gload16/wave (hbT, L2-hot). Ring-3, counted vmcnt(1).
__global__ __launch_bounds__(512, 4) void k_flash(
    const unsigned* __restrict__ bm, const unsigned short* __restrict__ hbT,
    const float* __restrict__ s1, const float* __restrict__ s2,
    const unsigned* __restrict__ gmxu,
    __half* __restrict__ num, float* __restrict__ lC)
{
    __shared__ __align__(16) unsigned short hbtring[3][4096]; // 8KB/slot
    __shared__ __align__(16) unsigned       bmlds[ROWS][28];  // 24 + pad (2-way, free)
    __shared__ __align__(16) float          s1lds[CW];

    const int t    = threadIdx.x;
    const int wid  = t >> 6, lane = t & 63;
    const int r    = lane & 15, g = lane >> 4;
    const int rowb = blockIdx.x * ROWS;
    const int prow = rowb + wid * 16 + r;
    const int chunk = blockIdx.y;
    const int j0 = chunk * CW;

    // one-time: stage s1 chunk + bitmask tile [128 rows][24 words]
    if (t < CW / 4) *(float4*)&s1lds[t * 4] = *(const float4*)(s1 + j0 + t * 4);
#pragma unroll
    for (int i = 0; i < 2; ++i) {
        int idx = i * 512 + t;               // 768 uint4 = 128 rows x 6
        if (idx < 768) {
            int brow = idx / 6, bk = idx % 6;
            uint4 w = *(const uint4*)(bm + (size_t)(rowb + brow) * BMW + chunk * NSTEP + bk * 4);
            *(uint4*)&bmlds[brow][bk * 4] = w;   // 28%4==0 -> 16B aligned
        }
    }

    const float gm  = funmap(gmxu[0]);
    const float s2r = s2[prow];
    const float zub = s2r + gm;
    const float Mi  = fmaxf(zub, 0.2f * zub);   // lrelu(ub) >= every row logit (log2 dom)
    const float nC1 = s2r - Mi, nC2 = 0.2f * s2r - Mi;

    // ---- hbT staging: wave wid stages feats wid*16..+16 via 1 gload16
    const int hrow  = wid * 16 + (lane >> 2);
    const int hcol8 = ((lane & 3) ^ ((lane >> 3) & 3)) * 8;
    const unsigned short* hgp0 = hbT + (size_t)hrow * NR + j0 + hcol8;
    const int hldso0 = wid * 16 * 64;
    const int h_base = r * 64 + ((g ^ ((r >> 1) & 3)) * 16);    // + f*1024

#define ISSUE(st) do { \
        const int sl_ = (st) % 3; \
        const size_t go_ = (size_t)(((st) % NSTEP) * 32); \
        gload16(hgp0 + go_, (char*)&hbtring[sl_][0] + hldso0); \
    } while (0)

    float lsum = 0.f;
    f32x4 acc[8];
#pragma unroll
    for (int f = 0; f < 8; ++f) acc[f] = f32x4{0.f, 0.f, 0.f, 0.f};

    ISSUE(0);
    ISSUE(1);

    const unsigned* bmrow = &bmlds[wid * 16 + r][0];
    const unsigned gsh = g * 8;

    for (int j = 0; j < NSTEP; ++j) {
        // stage j landed when <=1 of this wave's vmem remain (stage j+1 only).
        asm volatile("s_waitcnt vmcnt(1) lgkmcnt(0)" ::: "memory");
        __builtin_amdgcn_s_barrier();
        __builtin_amdgcn_sched_barrier(0);
        ISSUE(j + 2);   // slot (j+2)%3 == (j-1)%3, consumed before the barrier

        const unsigned mw = bmrow[j] >> gsh;    // bits 0..7 = this lane's 8 cols
        const float4 Sa = *(const float4*)&s1lds[j * 32 + g * 8];
        const float4 Sb = *(const float4*)&s1lds[j * 32 + g * 8 + 4];

        bf16x8 pf;
#define PROC(bi, ss, idx) { \
            float a_ = (ss) + nC1; \
            float b_ = __builtin_fmaf(0.2f, (ss), nC2); \
            float q  = fexp2(fmaxf(a_, b_)); \
            float p  = ((mw >> (bi)) & 1u) ? q : 0.f; \
            lsum += p; \
            pf[idx] = (__bf16)p; }
        PROC(0, Sa.x, 0) PROC(1, Sa.y, 1)
        PROC(2, Sa.z, 2) PROC(3, Sa.w, 3)
        PROC(4, Sb.x, 4) PROC(5, Sb.y, 5)
        PROC(6, Sb.z, 6) PROC(7, Sb.w, 7)
#undef PROC

        const int sl = j % 3;
        const char* hb = (const char*)&hbtring[sl][0] + h_base;
#pragma unroll
        for (int f = 0; f < 8; ++f) {
            bf16x8 bfr = *(const bf16x8*)(hb + f * 1024);
            acc[f] = __builtin_amdgcn_mfma_f32_16x16x32_bf16(pf, bfr, acc[f], 0, 0, 0);
        }
    }
#undef ISSUE

    lsum += __shfl_xor(lsum, 16);
    lsum += __shfl_xor(lsum, 32);
    if (g == 0) lC[(size_t)chunk * NR + prow] = lsum;

    __half* nb = num + (size_t)chunk * NR * DF;
#pragma unroll
    for (int f = 0; f < 8; ++f)
#pragma unroll
        for (int q = 0; q < 4; ++q) {
            int row = rowb + wid * 16 + g * 4 + q;   // C/D layout: row=(lane>>4)*4+reg
            nb[(size_t)row * DF + f * 16 + r] = __float2half(acc[f][q]);
        }
}

// ---------- Kernel C: combine chunk partials (shared M_i -> plain sums) ------
__global__ __launch_bounds__(256) void k_comb(
    const __half* __restrict__ num, const float* __restrict__ lC,
    float* __restrict__ out)
{
    const int t   = threadIdx.x;
    const int row = blockIdx.x * 2 + (t >> 7);
    const int f   = t & 127;
    float L = 0.f, o = 0.f;
    for (int c = 0; c < CH; ++c) {
        L += lC[(size_t)c * NR + row];
        o += __half2float(num[(size_t)c * NR * DF + (size_t)row * DF + f]);
    }
    out[(size_t)row * DF + f] = o / L;
}

extern "C" void kernel_launch(void* const* d_in, const int* in_sizes, int n_in,
                              void* d_out, int out_size, void* d_ws, size_t ws_size,
                              hipStream_t stream)
{
    const float* x   = (const float*)d_in[0];
    const int*   adj = (const int*)d_in[1];
    const float* W   = (const float*)d_in[2];
    const float* a1  = (const float*)d_in[3];
    const float* a2  = (const float*)d_in[4];
    float* out = (float*)d_out;

    char* p = (char*)d_ws;
    unsigned short* hbT = (unsigned short*)p; p += (size_t)DF * NR * 2;
    unsigned*       bmw = (unsigned*)p;       p += (size_t)NR * BMW * 4;
    float*          s1  = (float*)p;          p += (size_t)NR * 4;
    float*          s2  = (float*)p;          p += (size_t)NR * 4;
    unsigned*       gmxu = (unsigned*)p;      p += 256;
    __half*         numb = (__half*)p;        p += (size_t)CH * NR * DF * 2;
    float*          lC   = (float*)p;

    k_compress<<<2048, 256, 0, stream>>>(adj, bmw, gmxu);
    k_gemm_h<<<NR / 64, 256, 0, stream>>>(x, W, a1, a2, hbT, s1, s2, gmxu);
    k_flash<<<dim3(NR / ROWS, CH), 512, 0, stream>>>(bmw, hbT, s1, s2, gmxu, numb, lC);
    k_comb<<<NR / 2, 256, 0, stream>>>(numb, lC, out);
}